// Round 19
// baseline (179.138 us; speedup 1.0000x reference)
//
#include <hip/hip_runtime.h>
#include <stdint.h>

#define NPTS 262144
#define NB 4
#define KSEL 4096
#define CAP 8192
#define SLICE_LEN 1024
#define CBLK 128                   // compact blocks per batch
#define HBLK 64                    // score blocks per batch
#define NBIN 8192                  // 13-bit prefix bins (key >> 19)

// ---- workspace layout (bytes) ----
#define OFF_BITS  0ULL
#define OFF_H13   (4ULL*NPTS*NB)                       // 4 MB (keys)
#define OFF_SFX   (OFF_H13 + 4ULL*NBIN*NB)             // +128 KB h13
#define OFF_BCNT  (OFF_SFX + 4ULL*NBIN*NB)             // +128 KB sfx
#define OFF_CTRL  (OFF_BCNT + 4ULL*NBIN*NB)            // +128 KB bcnt
#define OFF_CAND  (OFF_CTRL + 1024ULL)
#define OFF_GRANK (OFF_CAND + 8ULL*CAP*NB)             // +256 KB cand
#define WS_NEEDED (OFF_GRANK + 4ULL*CAP*NB)            // +128 KB grank

// ---- output layout (float elements) ----
#define OBIN 0
#define ORES (NB*KSEL*5)           // 81920
#define OBOX (ORES + NB*KSEL)      // 98304
#define OCLS (OBOX + NB*KSEL*7)    // 212992

// ctrl per batch (64 u32): [3]=cand_count (plain-stored by compact bx0)

__device__ __forceinline__ uint32_t key_of(float mx) {
    uint32_t b = __float_as_uint(mx);
    uint32_t mask = ((int32_t)b >> 31) | 0x80000000u;
    return b ^ mask;
}

// parallel suffix scan over part[0..255] (part[256] must be 0)
__device__ __forceinline__ void suffix_scan_256(volatile uint32_t* part, int tid) {
    #pragma unroll
    for (int off = 1; off < 256; off <<= 1) {
        uint32_t v = part[tid] + ((tid + off < 256) ? part[tid + off] : 0u);
        __syncthreads();
        part[tid] = v;
        __syncthreads();
    }
}

// ---------------- init: zero h13 + bcnt ----------------
__global__ __launch_bounds__(256) void k_init(uint4* __restrict__ h13v, uint4* __restrict__ bcntv)
{
    int bx = blockIdx.x, tid = threadIdx.x;
    uint4 z = make_uint4(0u, 0u, 0u, 0u);
    if (bx < 32) h13v[bx * 256 + tid] = z;             // 8192 uint4 = 128 KB
    else         bcntv[(bx - 32) * 256 + tid] = z;
}

// ---------------- keys + 13-bit LDS histogram ----------------
__global__ __launch_bounds__(256) void k_score(
    const float* __restrict__ cls, uint32_t* __restrict__ bits, uint32_t* __restrict__ h13)
{
    __shared__ uint32_t lh[NBIN];                      // 32 KB
    int b = blockIdx.y, bx = blockIdx.x, tid = threadIdx.x;
    for (int i = tid; i < NBIN; i += 256) lh[i] = 0;
    __syncthreads();
    for (int it = 0; it < 4; ++it) {
        int chunk = bx * 1024 + it * 256 + tid;        // uint4-chunk in [0,65536)
        const float4* p = (const float4*)(cls + ((size_t)b * NPTS + (size_t)chunk * 4) * 3);
        float4 v0 = p[0], v1 = p[1], v2 = p[2];
        uint4 o;
        o.x = key_of(fmaxf(fmaxf(v0.x, v0.y), v0.z));
        o.y = key_of(fmaxf(fmaxf(v0.w, v1.x), v1.y));
        o.z = key_of(fmaxf(fmaxf(v1.z, v1.w), v2.x));
        o.w = key_of(fmaxf(fmaxf(v2.y, v2.z), v2.w));
        ((uint4*)(bits + (size_t)b * NPTS))[chunk] = o;
        atomicAdd(&lh[o.x >> 19], 1u);
        atomicAdd(&lh[o.y >> 19], 1u);
        atomicAdd(&lh[o.z >> 19], 1u);
        atomicAdd(&lh[o.w >> 19], 1u);
    }
    __syncthreads();
    uint32_t* h13b = h13 + (size_t)b * NBIN;
    for (int i = tid; i < NBIN; i += 256) {
        uint32_t c = lh[i];
        if (c) atomicAdd(&h13b[i], c);                 // sparse flush
    }
}

// ---------------- compact: inline scan -> T13; bin-sorted scatter; bx0 writes sfx+C ----
__global__ __launch_bounds__(256) void k_compact(
    const uint32_t* __restrict__ bits, const uint32_t* __restrict__ h13,
    uint32_t* __restrict__ sfx, uint32_t* __restrict__ bcnt,
    uint32_t* __restrict__ ctrl, uint64_t* __restrict__ cand)
{
    __shared__ uint32_t bins[NBIN];                    // 32 KB
    __shared__ uint32_t lha[NBIN];                     // 32 KB: block bin-counts -> bases
    __shared__ uint32_t part[257];
    __shared__ uint32_t segS, Ts;
    int b = blockIdx.y, bx = blockIdx.x, tid = threadIdx.x;
    const uint4* src = (const uint4*)(h13 + (size_t)b * NBIN);
    for (int i = tid; i < NBIN / 4; i += 256) ((uint4*)bins)[i] = src[i];
    for (int i = tid; i < NBIN; i += 256) lha[i] = 0;
    __syncthreads();
    {
        uint32_t s = 0;
        int base2 = tid * 32;
        #pragma unroll
        for (int j = 0; j < 32; ++j) s += bins[base2 + j];
        part[tid] = s;
        if (tid == 0) part[256] = 0u;
    }
    __syncthreads();
    suffix_scan_256(part, tid);                        // part[t] = count(bin >= t*32)
    {
        uint32_t si = part[tid], sn = part[tid + 1];
        if (si >= (uint32_t)KSEL && sn < (uint32_t)KSEL) segS = (uint32_t)tid;
    }
    __syncthreads();
    if (tid < 32) {
        uint32_t seg = segS;
        uint32_t above = part[seg + 1];
        uint32_t cnt = above;
        for (int j = 31; j >= tid; --j) cnt += bins[seg * 32 + j];
        uint32_t cntn = cnt - bins[seg * 32 + tid];
        if (cnt >= (uint32_t)KSEL && cntn < (uint32_t)KSEL)
            Ts = seg * 32 + (uint32_t)tid;             // T13
    }
    __syncthreads();
    const uint32_t T = Ts;
    // bx0: persist suffix array sfx[x] = count(bin >= x), and C
    if (bx == 0) {
        uint32_t run = part[tid + 1];
        uint32_t* sb2 = sfx + (size_t)b * NBIN + tid * 32;
        for (int j = 31; j >= 0; --j) {
            run += bins[tid * 32 + j];
            sb2[j] = run;
        }
        if (tid == 0) {
            uint32_t seg = T >> 5, run2 = part[seg + 1];
            for (int j = 31; j >= (int)(T & 31u); --j) run2 += bins[seg * 32 + j];
            ctrl[b * 64 + 3] = (run2 > (uint32_t)CAP) ? (uint32_t)CAP : run2;
        }
    }

    // ---- select ----
    int chunk0 = bx * 512 + tid;
    const uint4* sb = (const uint4*)(bits + (size_t)b * NPTS);
    uint4 v0 = sb[chunk0];
    uint4 v1 = sb[chunk0 + 256];
    uint32_t ks[8] = {v0.x, v0.y, v0.z, v0.w, v1.x, v1.y, v1.z, v1.w};
    bool sel[8];
    #pragma unroll
    for (int i = 0; i < 8; ++i) sel[i] = (ks[i] >> 19) >= T;

    // per-block bin counts in LDS
    #pragma unroll
    for (int i = 0; i < 8; ++i)
        if (sel[i]) atomicAdd(&lha[ks[i] >> 19], 1u);
    __syncthreads();
    // flush nonzero counts -> global bcnt; store returned base back into lha
    {
        uint32_t* bc = bcnt + (size_t)b * NBIN;
        for (int i = tid; i < NBIN; i += 256) {
            uint32_t c = lha[i];
            if (c) lha[i] = atomicAdd(&bc[i], c);
        }
    }
    __syncthreads();
    // scatter bin-sorted: pos = sfx(bin+1) + base + local offset
    #pragma unroll
    for (int i = 0; i < 8; ++i) {
        if (sel[i]) {
            uint32_t bin = ks[i] >> 19;
            uint32_t lo = 0;
            if (bin < NBIN - 1) {
                uint32_t x = bin + 1, seg = x >> 5;
                lo = part[seg + 1];
                for (int j = 31; j >= (int)(x & 31u); --j) lo += bins[seg * 32 + j];
            }
            uint32_t pos = lo + atomicAdd(&lha[bin], 1u);
            uint32_t n = (uint32_t)(chunk0 + (i < 4 ? 0 : 256)) * 4 + (uint32_t)(i & 3);
            if (pos < CAP)
                cand[(size_t)b * CAP + pos] = ((uint64_t)(~ks[i]) << 32) | (uint64_t)n;
        }
    }
}

// ---------------- segmented rank: compare only within own bin's segment ----------------
// grid (CAP/256, NB); grank written by plain store (no atomics, no zeroing)
__global__ __launch_bounds__(256) void k_rank1(
    const uint64_t* __restrict__ cand, const uint32_t* __restrict__ ctrl,
    const uint32_t* __restrict__ sfx, uint32_t* __restrict__ grank)
{
    __shared__ uint64_t keys[SLICE_LEN];
    __shared__ uint32_t loMinS, hiMaxS;
    int b = blockIdx.y, tid = threadIdx.x;
    uint32_t C = ctrl[b * 64 + 3];
    if (C > CAP) C = CAP;
    uint32_t ig0 = blockIdx.x * 256;
    if (ig0 >= C) return;
    const uint64_t* cb = cand + (size_t)b * CAP;
    uint32_t item = ig0 + tid;
    bool valid = (item < C);
    uint64_t me = valid ? cb[item] : ~0ull;
    uint32_t ksv = ~(uint32_t)(me >> 32);
    uint32_t bin = ksv >> 19;
    const uint32_t* sfb = sfx + (size_t)b * NBIN;
    uint32_t lo = 0, hi = 0;
    if (valid) {
        lo = (bin >= NBIN - 1) ? 0u : sfb[bin + 1];
        hi = sfb[bin];
        if (lo > C) lo = C;
        if (hi > C) hi = C;
    }
    if (tid == 0) { loMinS = 0xFFFFFFFFu; hiMaxS = 0u; }
    __syncthreads();
    if (valid) { atomicMin(&loMinS, lo); atomicMax(&hiMaxS, hi); }
    __syncthreads();
    uint32_t r = lo;                       // all candidates in higher bins rank before me
    for (uint32_t s0 = loMinS; s0 < hiMaxS; s0 += SLICE_LEN) {
        uint32_t nk = hiMaxS - s0; if (nk > SLICE_LEN) nk = SLICE_LEN;
        for (uint32_t i = tid; i < nk; i += 256) keys[i] = cb[s0 + i];
        __syncthreads();
        if (valid && hi > s0 && lo < s0 + nk) {
            uint32_t a = (lo > s0) ? (lo - s0) : 0u;
            uint32_t e = hi - s0; if (e > nk) e = nk;
            for (uint32_t i = a; i < e; ++i) r += (keys[i] < me) ? 1u : 0u;
        }
        __syncthreads();
    }
    if (valid) grank[b * CAP + item] = r;  // plain store
}

// ---------------- gather by rank ----------------
__global__ __launch_bounds__(256) void k_rank2(
    const uint64_t* __restrict__ cand, const uint32_t* __restrict__ ctrl,
    const uint32_t* __restrict__ grank,
    const float* __restrict__ box, const float* __restrict__ cls, float* __restrict__ out)
{
    int b = blockIdx.y;
    uint32_t C = ctrl[b * 64 + 3];
    if (C > CAP) C = CAP;
    uint32_t item = blockIdx.x * 256 + threadIdx.x;
    if (blockIdx.x * 256 >= C) return;
    if (item >= C) return;
    uint64_t me = cand[(size_t)b * CAP + item];
    uint32_t rank = grank[b * CAP + item];
    if (rank < KSEL) {
        uint32_t n = (uint32_t)me;
        const float* bp = box + ((size_t)b * NPTS + n) * 7;
        float* ob = out + OBOX + ((size_t)b * KSEL + rank) * 7;
        #pragma unroll
        for (int c = 0; c < 7; ++c) ob[c] = bp[c];
        const float* cp = cls + ((size_t)b * NPTS + n) * 3;
        float* oc = out + OCLS + ((size_t)b * KSEL + rank) * 3;
        #pragma unroll
        for (int c = 0; c < 3; ++c) oc[c] = cp[c];
    }
}

// ---------------- fused conv1+bn+relu+conv2+bn+relu+heads (tile 64) ----------------
__global__ __launch_bounds__(256) void k_conv(
    const float* __restrict__ c1w, const float* __restrict__ g1v, const float* __restrict__ b1v,
    const float* __restrict__ m1v, const float* __restrict__ v1v,
    const float* __restrict__ c2w, const float* __restrict__ g2v, const float* __restrict__ b2v,
    const float* __restrict__ m2v, const float* __restrict__ v2v,
    const float* __restrict__ binw, const float* __restrict__ binb,
    const float* __restrict__ resw, const float* __restrict__ resb,
    float* __restrict__ out)
{
    __shared__ __align__(16) float w1s[960];       // [(i*3+tap)*32 + c]
    __shared__ __align__(16) float b1s[32];
    __shared__ __align__(16) float w2s[6144];      // [(i*3+tap)*64 + o]
    __shared__ __align__(16) float b2s[64];
    __shared__ __align__(16) float hws[6][64];     // bin0..4, res
    __shared__ __align__(16) float xin[10][80];
    __shared__ __align__(16) float x1s[32][68];
    __shared__ __align__(16) float x2t[64][68];

    int tid = threadIdx.x;
    int b = blockIdx.y;
    int tile0 = blockIdx.x * 64;
    const float* boxsel = out + OBOX + (size_t)b * KSEL * 7;
    const float* clssel = out + OCLS + (size_t)b * KSEL * 3;

    for (int t = tid; t < 960; t += 256) {
        int c = t / 30, r = t - c * 30, i = r / 3, tap = r - i * 3;
        float inv = g1v[c] * rsqrtf(v1v[c] + 1e-5f);
        w1s[(i * 3 + tap) * 32 + c] = c1w[t] * inv;
    }
    if (tid < 32) {
        float inv = g1v[tid] * rsqrtf(v1v[tid] + 1e-5f);
        b1s[tid] = b1v[tid] - m1v[tid] * inv;
    }
    for (int t = tid; t < 6144; t += 256) {
        int o = t / 96, r = t - o * 96, i = r / 3, tap = r - i * 3;
        float inv = g2v[o] * rsqrtf(v2v[o] + 1e-5f);
        w2s[(i * 3 + tap) * 64 + o] = c2w[t] * inv;
    }
    if (tid >= 64 && tid < 128) {
        int o = tid - 64;
        float inv = g2v[o] * rsqrtf(v2v[o] + 1e-5f);
        b2s[o] = b2v[o] - m2v[o] * inv;
    }
    for (int t = tid; t < 384; t += 256)
        ((float*)hws)[t] = (t < 320) ? binw[t] : resw[t - 320];

    for (int u = tid; u < 680; u += 256) {
        int c = u / 68, k2 = u - c * 68;
        int g = tile0 + k2 - 2;
        float val = 0.f;
        if (g >= 0 && g < KSEL) val = (c < 7) ? boxsel[g * 7 + c] : clssel[g * 3 + (c - 7)];
        xin[c][k2] = val;
    }
    __syncthreads();

    {
        int c = tid & 31, kg = tid >> 5;
        int k0 = kg * 9;
        int nk = 66 - k0; if (nk > 9) nk = 9;
        float a[9];
        #pragma unroll
        for (int kk = 0; kk < 9; ++kk) a[kk] = b1s[c];
        #pragma unroll 2
        for (int i = 0; i < 10; ++i) {
            float xv[11];
            #pragma unroll
            for (int j = 0; j < 11; ++j) xv[j] = xin[i][k0 + j];
            #pragma unroll
            for (int tap = 0; tap < 3; ++tap) {
                float w = w1s[(i * 3 + tap) * 32 + c];
                #pragma unroll
                for (int kk = 0; kk < 9; ++kk) a[kk] = fmaf(w, xv[kk + tap], a[kk]);
            }
        }
        for (int kk = 0; kk < nk; ++kk) {
            int k = k0 + kk, gp = tile0 + k - 1;
            x1s[c][k] = (gp >= 0 && gp < KSEL) ? fmaxf(a[kk], 0.f) : 0.f;
        }
    }
    __syncthreads();

    {
        int o = tid & 63, pg = tid >> 6;
        int p0 = pg * 16;
        float acc[16];
        float bz = b2s[o];
        #pragma unroll
        for (int kk = 0; kk < 16; ++kk) acc[kk] = bz;
        #pragma unroll 4
        for (int i = 0; i < 32; ++i) {
            float4 xq[5];
            const float4* xr = (const float4*)&x1s[i][p0];
            #pragma unroll
            for (int q = 0; q < 5; ++q) xq[q] = xr[q];
            const float* xf = (const float*)xq;
            float w0 = w2s[(i * 3 + 0) * 64 + o];
            float w1 = w2s[(i * 3 + 1) * 64 + o];
            float w2 = w2s[(i * 3 + 2) * 64 + o];
            #pragma unroll
            for (int kk = 0; kk < 16; ++kk) {
                float t0 = fmaf(w0, xf[kk], acc[kk]);
                t0 = fmaf(w1, xf[kk + 1], t0);
                acc[kk] = fmaf(w2, xf[kk + 2], t0);
            }
        }
        #pragma unroll
        for (int kk = 0; kk < 16; ++kk)
            x2t[p0 + kk][o] = fmaxf(acc[kk], 0.f);
    }
    __syncthreads();

    {
        int p = tid & 63, g = tid >> 6;
        const float4* xr = (const float4*)&x2t[p][0];
        const float4* hw4 = (const float4*)hws;
        size_t gpos = (size_t)b * KSEL + (size_t)(tile0 + p);
        if (g < 2) {
            int j0 = g * 2, j1 = j0 + 1;
            float s0 = 0.f, s1 = 0.f;
            #pragma unroll
            for (int q = 0; q < 16; ++q) {
                float4 xv = xr[q];
                float4 wa = hw4[j0 * 16 + q];
                float4 wb = hw4[j1 * 16 + q];
                s0 = fmaf(xv.x, wa.x, s0); s0 = fmaf(xv.y, wa.y, s0);
                s0 = fmaf(xv.z, wa.z, s0); s0 = fmaf(xv.w, wa.w, s0);
                s1 = fmaf(xv.x, wb.x, s1); s1 = fmaf(xv.y, wb.y, s1);
                s1 = fmaf(xv.z, wb.z, s1); s1 = fmaf(xv.w, wb.w, s1);
            }
            out[OBIN + gpos * 5 + j0] = s0 + binb[j0];
            out[OBIN + gpos * 5 + j1] = s1 + binb[j1];
        } else {
            int j = (g == 2) ? 4 : 5;
            float s = 0.f;
            #pragma unroll
            for (int q = 0; q < 16; ++q) {
                float4 xv = xr[q];
                float4 wa = hw4[j * 16 + q];
                s = fmaf(xv.x, wa.x, s); s = fmaf(xv.y, wa.y, s);
                s = fmaf(xv.z, wa.z, s); s = fmaf(xv.w, wa.w, s);
            }
            if (g == 2) out[OBIN + gpos * 5 + 4] = s + binb[4];
            else        out[ORES + gpos]         = s + resb[0];
        }
    }
}

extern "C" void kernel_launch(void* const* d_in, const int* in_sizes, int n_in,
                              void* d_out, int out_size, void* d_ws, size_t ws_size,
                              hipStream_t stream)
{
    const float* box  = (const float*)d_in[0];
    const float* cls  = (const float*)d_in[1];
    const float* c1w  = (const float*)d_in[2];
    const float* g1   = (const float*)d_in[3];
    const float* b1   = (const float*)d_in[4];
    const float* m1   = (const float*)d_in[5];
    const float* v1   = (const float*)d_in[6];
    const float* c2w  = (const float*)d_in[7];
    const float* g2   = (const float*)d_in[8];
    const float* b2   = (const float*)d_in[9];
    const float* m2   = (const float*)d_in[10];
    const float* v2   = (const float*)d_in[11];
    const float* binw = (const float*)d_in[12];
    const float* binb = (const float*)d_in[13];
    const float* resw = (const float*)d_in[14];
    const float* resb = (const float*)d_in[15];
    float* out = (float*)d_out;
    char* ws = (char*)d_ws;
    if (ws_size < WS_NEEDED) return;

    uint32_t* bits  = (uint32_t*)(ws + OFF_BITS);
    uint32_t* h13   = (uint32_t*)(ws + OFF_H13);
    uint32_t* sfx   = (uint32_t*)(ws + OFF_SFX);
    uint32_t* bcnt  = (uint32_t*)(ws + OFF_BCNT);
    uint32_t* ctrl  = (uint32_t*)(ws + OFF_CTRL);
    uint64_t* cand  = (uint64_t*)(ws + OFF_CAND);
    uint32_t* grank = (uint32_t*)(ws + OFF_GRANK);

    k_init<<<64, 256, 0, stream>>>((uint4*)h13, (uint4*)bcnt);
    k_score<<<dim3(HBLK, NB), 256, 0, stream>>>(cls, bits, h13);
    k_compact<<<dim3(CBLK, NB), 256, 0, stream>>>(bits, h13, sfx, bcnt, ctrl, cand);
    k_rank1<<<dim3(CAP / 256, NB), 256, 0, stream>>>(cand, ctrl, sfx, grank);
    k_rank2<<<dim3(CAP / 256, NB), 256, 0, stream>>>(cand, ctrl, grank, box, cls, out);
    k_conv<<<dim3(64, NB), 256, 0, stream>>>(c1w, g1, b1, m1, v1, c2w, g2, b2, m2, v2,
                                             binw, binb, resw, resb, out);
}

// Round 20
// 68.483 us; speedup vs baseline: 2.6158x; 2.6158x over previous
//
#include <hip/hip_runtime.h>
#include <stdint.h>

#define NPTS 262144
#define NB 4
#define KSEL 4096
#define CAP 8192
#define SLICE_LEN 1024
#define CBLK 128                   // compact blocks per batch
#define HBLK 64                    // score blocks per batch
#define NBIN 8192                  // 13-bit prefix bins (key >> 19)

// ---- workspace layout (bytes) ----
#define OFF_BITS  0ULL
#define OFF_H13   (4ULL*NPTS*NB)                       // 4 MB (keys)
#define OFF_CTRL  (OFF_H13 + 4ULL*NBIN*NB)             // +128 KB h13
#define OFF_GRANK (OFF_CTRL + 1024ULL)
#define OFF_CAND  (OFF_GRANK + 4ULL*CAP*NB)            // +128 KB
#define WS_NEEDED (OFF_CAND + 8ULL*CAP*NB)             // +256 KB

// ---- output layout (float elements) ----
#define OBIN 0
#define ORES (NB*KSEL*5)           // 81920
#define OBOX (ORES + NB*KSEL)      // 98304
#define OCLS (OBOX + NB*KSEL*7)    // 212992

// ctrl per batch (16 u32): [3]=cand_count

__device__ __forceinline__ uint32_t key_of(float mx) {
    uint32_t b = __float_as_uint(mx);
    uint32_t mask = ((int32_t)b >> 31) | 0x80000000u;
    return b ^ mask;
}

// parallel suffix scan over part[0..255] (part[256] must be 0)
__device__ __forceinline__ void suffix_scan_256(volatile uint32_t* part, int tid) {
    #pragma unroll
    for (int off = 1; off < 256; off <<= 1) {
        uint32_t v = part[tid] + ((tid + off < 256) ? part[tid + off] : 0u);
        __syncthreads();
        part[tid] = v;
        __syncthreads();
    }
}

// ---------------- init: zero h13 (8 blocks, one uint4/thread) ----------------
__global__ __launch_bounds__(256) void k_init(uint4* __restrict__ h13v)
{
    h13v[blockIdx.x * 256 + threadIdx.x] = make_uint4(0u, 0u, 0u, 0u);
}

// ---------------- keys + 13-bit LDS histogram (full coverage, no window) ----------------
__global__ __launch_bounds__(256) void k_score(
    const float* __restrict__ cls, uint32_t* __restrict__ bits, uint32_t* __restrict__ h13,
    uint32_t* __restrict__ grank, uint32_t* __restrict__ ctrl)
{
    __shared__ uint32_t lh[NBIN];                      // 32 KB
    for (int i = threadIdx.x; i < NBIN; i += 256) lh[i] = 0;
    __syncthreads();
    int b = blockIdx.y, bx = blockIdx.x;
    for (int it = 0; it < 4; ++it) {
        int chunk = bx * 1024 + it * 256 + threadIdx.x;            // uint4-chunk in [0,65536)
        const float4* p = (const float4*)(cls + ((size_t)b * NPTS + (size_t)chunk * 4) * 3);
        float4 v0 = p[0], v1 = p[1], v2 = p[2];
        uint4 o;
        o.x = key_of(fmaxf(fmaxf(v0.x, v0.y), v0.z));
        o.y = key_of(fmaxf(fmaxf(v0.w, v1.x), v1.y));
        o.z = key_of(fmaxf(fmaxf(v1.z, v1.w), v2.x));
        o.w = key_of(fmaxf(fmaxf(v2.y, v2.z), v2.w));
        ((uint4*)(bits + (size_t)b * NPTS))[chunk] = o;
        atomicAdd(&lh[o.x >> 19], 1u);
        atomicAdd(&lh[o.y >> 19], 1u);
        atomicAdd(&lh[o.z >> 19], 1u);
        atomicAdd(&lh[o.w >> 19], 1u);
    }
    // folded zeroing (visible to later dispatches)
    if (bx == 1) {
        uint4* zg = (uint4*)(grank + (size_t)b * CAP);
        #pragma unroll
        for (int i = 0; i < 8; ++i) zg[threadIdx.x + i * 256] = make_uint4(0u, 0u, 0u, 0u);
    } else if (bx == 2 && threadIdx.x == 0) {
        ctrl[b * 16 + 3] = 0u;
    }
    __syncthreads();
    uint32_t* h13b = h13 + (size_t)b * NBIN;
    for (int i = threadIdx.x; i < NBIN; i += 256) {
        uint32_t c = lh[i];
        if (c) atomicAdd(&h13b[i], c);                 // sparse: few hundred nonzero/block
    }
}

// ---------------- compact: inline parallel scan of 8192 bins -> T13; compact ----------------
__global__ __launch_bounds__(256) void k_compact(
    const uint32_t* __restrict__ bits, const uint32_t* __restrict__ h13,
    uint32_t* __restrict__ ctrl, uint64_t* __restrict__ cand)
{
    __shared__ uint32_t bins[NBIN];                    // 32 KB
    __shared__ uint32_t part[257];
    __shared__ uint32_t segS, Ts;
    __shared__ uint32_t wbase[4];
    int b = blockIdx.y, bx = blockIdx.x;
    int tid = threadIdx.x;
    const uint4* src = (const uint4*)(h13 + (size_t)b * NBIN);
    for (int i = tid; i < NBIN / 4; i += 256) ((uint4*)bins)[i] = src[i];
    __syncthreads();
    {
        uint32_t s = 0;
        int base2 = tid * 32;
        #pragma unroll
        for (int j = 0; j < 32; ++j) s += bins[base2 + j];
        part[tid] = s;
        if (tid == 0) part[256] = 0u;
    }
    __syncthreads();
    suffix_scan_256(part, tid);                        // part[t] = count(bin >= t*32)
    {
        uint32_t si = part[tid], sn = part[tid + 1];
        if (si >= (uint32_t)KSEL && sn < (uint32_t)KSEL) segS = (uint32_t)tid;
    }
    __syncthreads();
    if (tid < 32) {
        uint32_t seg = segS;
        uint32_t above = part[seg + 1];
        uint32_t cnt = above;
        for (int j = 31; j >= tid; --j) cnt += bins[seg * 32 + j];
        uint32_t cntn = cnt - bins[seg * 32 + tid];
        if (cnt >= (uint32_t)KSEL && cntn < (uint32_t)KSEL)
            Ts = seg * 32 + (uint32_t)tid;             // T13
    }
    __syncthreads();
    const uint32_t T = Ts;
    const int lane = tid & 63, wave = tid >> 6;
    const uint64_t lmask = (1ull << lane) - 1ull;

    int chunk0 = bx * 512 + tid;
    const uint4* sb = (const uint4*)(bits + (size_t)b * NPTS);
    uint4 v0 = sb[chunk0];
    uint4 v1 = sb[chunk0 + 256];
    uint32_t ks[8] = {v0.x, v0.y, v0.z, v0.w, v1.x, v1.y, v1.z, v1.w};
    bool sel[8];
    #pragma unroll
    for (int i = 0; i < 8; ++i) sel[i] = (ks[i] >> 19) >= T;

    uint32_t wsum = 0;
    #pragma unroll
    for (int i = 0; i < 8; ++i) wsum += (uint32_t)__popcll(__ballot(sel[i]));
    if (lane == 0) wbase[wave] = wsum;
    __syncthreads();
    if (tid == 0) {
        uint32_t c0 = wbase[0], c1 = wbase[1], c2 = wbase[2], c3 = wbase[3];
        uint32_t tot = c0 + c1 + c2 + c3;
        uint32_t base = tot ? atomicAdd(&ctrl[b * 16 + 3], tot) : 0u;
        wbase[0] = base;
        wbase[1] = base + c0;
        wbase[2] = base + c0 + c1;
        wbase[3] = base + c0 + c1 + c2;
    }
    __syncthreads();
    uint32_t off = wbase[wave];
    #pragma unroll
    for (int i = 0; i < 8; ++i) {
        uint64_t m = __ballot(sel[i]);
        if (sel[i]) {
            uint32_t pos = off + (uint32_t)__popcll(m & lmask);
            uint32_t n = (uint32_t)(chunk0 + (i < 4 ? 0 : 256)) * 4 + (uint32_t)(i & 3);
            if (pos < CAP)
                cand[(size_t)b * CAP + pos] = ((uint64_t)(~ks[i]) << 32) | (uint64_t)n;
        }
        off += (uint32_t)__popcll(m);
    }
}

// ---------------- partial ranks: 1 item/thread, 1024 blocks (4 blocks/CU TLP) ----------------
__global__ __launch_bounds__(256) void k_rank1(
    const uint64_t* __restrict__ cand, const uint32_t* __restrict__ ctrl,
    uint32_t* __restrict__ grank)
{
    __shared__ uint64_t keys[SLICE_LEN];
    int b = blockIdx.z;
    uint32_t C = ctrl[b * 16 + 3];
    if (C > CAP) C = CAP;
    uint32_t ig0 = blockIdx.x * 256;
    uint32_t sk0 = blockIdx.y * SLICE_LEN;
    if (ig0 >= C || sk0 >= C) return;                 // uniform early-exit
    uint32_t nk = C - sk0; if (nk > SLICE_LEN) nk = SLICE_LEN;
    const uint64_t* cb = cand + (size_t)b * CAP;
    for (uint32_t i = threadIdx.x; i < nk; i += 256) keys[i] = cb[sk0 + i];
    __syncthreads();
    uint32_t item = ig0 + threadIdx.x;
    if (item >= C) return;
    uint64_t me = cb[item];
    uint32_t r = 0;
    #pragma unroll 16
    for (uint32_t i = 0; i < nk; ++i) r += (keys[i] < me) ? 1u : 0u;
    atomicAdd(&grank[b * CAP + item], r);
}

// ---------------- gather by rank ----------------
__global__ __launch_bounds__(256) void k_rank2(
    const uint64_t* __restrict__ cand, const uint32_t* __restrict__ ctrl,
    const uint32_t* __restrict__ grank,
    const float* __restrict__ box, const float* __restrict__ cls, float* __restrict__ out)
{
    int b = blockIdx.y;
    uint32_t C = ctrl[b * 16 + 3];
    if (C > CAP) C = CAP;
    uint32_t item = blockIdx.x * 256 + threadIdx.x;
    if (blockIdx.x * 256 >= C) return;
    if (item >= C) return;
    uint64_t me = cand[(size_t)b * CAP + item];
    uint32_t rank = grank[b * CAP + item];
    if (rank < KSEL) {
        uint32_t n = (uint32_t)me;
        const float* bp = box + ((size_t)b * NPTS + n) * 7;
        float* ob = out + OBOX + ((size_t)b * KSEL + rank) * 7;
        #pragma unroll
        for (int c = 0; c < 7; ++c) ob[c] = bp[c];
        const float* cp = cls + ((size_t)b * NPTS + n) * 3;
        float* oc = out + OCLS + ((size_t)b * KSEL + rank) * 3;
        #pragma unroll
        for (int c = 0; c < 3; ++c) oc[c] = cp[c];
    }
}

// ---------------- fused conv1+bn+relu+conv2+bn+relu+heads (tile 64) ----------------
__global__ __launch_bounds__(256) void k_conv(
    const float* __restrict__ c1w, const float* __restrict__ g1v, const float* __restrict__ b1v,
    const float* __restrict__ m1v, const float* __restrict__ v1v,
    const float* __restrict__ c2w, const float* __restrict__ g2v, const float* __restrict__ b2v,
    const float* __restrict__ m2v, const float* __restrict__ v2v,
    const float* __restrict__ binw, const float* __restrict__ binb,
    const float* __restrict__ resw, const float* __restrict__ resb,
    float* __restrict__ out)
{
    __shared__ __align__(16) float w1s[960];       // [(i*3+tap)*32 + c]
    __shared__ __align__(16) float b1s[32];
    __shared__ __align__(16) float w2s[6144];      // [(i*3+tap)*64 + o]
    __shared__ __align__(16) float b2s[64];
    __shared__ __align__(16) float hws[6][64];     // bin0..4, res
    __shared__ __align__(16) float xin[10][80];
    __shared__ __align__(16) float x1s[32][68];
    __shared__ __align__(16) float x2t[64][68];

    int tid = threadIdx.x;
    int b = blockIdx.y;
    int tile0 = blockIdx.x * 64;
    const float* boxsel = out + OBOX + (size_t)b * KSEL * 7;
    const float* clssel = out + OCLS + (size_t)b * KSEL * 3;

    for (int t = tid; t < 960; t += 256) {
        int c = t / 30, r = t - c * 30, i = r / 3, tap = r - i * 3;
        float inv = g1v[c] * rsqrtf(v1v[c] + 1e-5f);
        w1s[(i * 3 + tap) * 32 + c] = c1w[t] * inv;
    }
    if (tid < 32) {
        float inv = g1v[tid] * rsqrtf(v1v[tid] + 1e-5f);
        b1s[tid] = b1v[tid] - m1v[tid] * inv;
    }
    for (int t = tid; t < 6144; t += 256) {
        int o = t / 96, r = t - o * 96, i = r / 3, tap = r - i * 3;
        float inv = g2v[o] * rsqrtf(v2v[o] + 1e-5f);
        w2s[(i * 3 + tap) * 64 + o] = c2w[t] * inv;
    }
    if (tid >= 64 && tid < 128) {
        int o = tid - 64;
        float inv = g2v[o] * rsqrtf(v2v[o] + 1e-5f);
        b2s[o] = b2v[o] - m2v[o] * inv;
    }
    for (int t = tid; t < 384; t += 256)
        ((float*)hws)[t] = (t < 320) ? binw[t] : resw[t - 320];

    for (int u = tid; u < 680; u += 256) {
        int c = u / 68, k2 = u - c * 68;
        int g = tile0 + k2 - 2;
        float val = 0.f;
        if (g >= 0 && g < KSEL) val = (c < 7) ? boxsel[g * 7 + c] : clssel[g * 3 + (c - 7)];
        xin[c][k2] = val;
    }
    __syncthreads();

    {
        int c = tid & 31, kg = tid >> 5;
        int k0 = kg * 9;
        int nk = 66 - k0; if (nk > 9) nk = 9;
        float a[9];
        #pragma unroll
        for (int kk = 0; kk < 9; ++kk) a[kk] = b1s[c];
        #pragma unroll 2
        for (int i = 0; i < 10; ++i) {
            float xv[11];
            #pragma unroll
            for (int j = 0; j < 11; ++j) xv[j] = xin[i][k0 + j];
            #pragma unroll
            for (int tap = 0; tap < 3; ++tap) {
                float w = w1s[(i * 3 + tap) * 32 + c];
                #pragma unroll
                for (int kk = 0; kk < 9; ++kk) a[kk] = fmaf(w, xv[kk + tap], a[kk]);
            }
        }
        for (int kk = 0; kk < nk; ++kk) {
            int k = k0 + kk, gp = tile0 + k - 1;
            x1s[c][k] = (gp >= 0 && gp < KSEL) ? fmaxf(a[kk], 0.f) : 0.f;
        }
    }
    __syncthreads();

    {
        int o = tid & 63, pg = tid >> 6;
        int p0 = pg * 16;
        float acc[16];
        float bz = b2s[o];
        #pragma unroll
        for (int kk = 0; kk < 16; ++kk) acc[kk] = bz;
        #pragma unroll 4
        for (int i = 0; i < 32; ++i) {
            float4 xq[5];
            const float4* xr = (const float4*)&x1s[i][p0];
            #pragma unroll
            for (int q = 0; q < 5; ++q) xq[q] = xr[q];
            const float* xf = (const float*)xq;
            float w0 = w2s[(i * 3 + 0) * 64 + o];
            float w1 = w2s[(i * 3 + 1) * 64 + o];
            float w2 = w2s[(i * 3 + 2) * 64 + o];
            #pragma unroll
            for (int kk = 0; kk < 16; ++kk) {
                float t0 = fmaf(w0, xf[kk], acc[kk]);
                t0 = fmaf(w1, xf[kk + 1], t0);
                acc[kk] = fmaf(w2, xf[kk + 2], t0);
            }
        }
        #pragma unroll
        for (int kk = 0; kk < 16; ++kk)
            x2t[p0 + kk][o] = fmaxf(acc[kk], 0.f);
    }
    __syncthreads();

    {
        int p = tid & 63, g = tid >> 6;
        const float4* xr = (const float4*)&x2t[p][0];
        const float4* hw4 = (const float4*)hws;
        size_t gpos = (size_t)b * KSEL + (size_t)(tile0 + p);
        if (g < 2) {
            int j0 = g * 2, j1 = j0 + 1;
            float s0 = 0.f, s1 = 0.f;
            #pragma unroll
            for (int q = 0; q < 16; ++q) {
                float4 xv = xr[q];
                float4 wa = hw4[j0 * 16 + q];
                float4 wb = hw4[j1 * 16 + q];
                s0 = fmaf(xv.x, wa.x, s0); s0 = fmaf(xv.y, wa.y, s0);
                s0 = fmaf(xv.z, wa.z, s0); s0 = fmaf(xv.w, wa.w, s0);
                s1 = fmaf(xv.x, wb.x, s1); s1 = fmaf(xv.y, wb.y, s1);
                s1 = fmaf(xv.z, wb.z, s1); s1 = fmaf(xv.w, wb.w, s1);
            }
            out[OBIN + gpos * 5 + j0] = s0 + binb[j0];
            out[OBIN + gpos * 5 + j1] = s1 + binb[j1];
        } else {
            int j = (g == 2) ? 4 : 5;
            float s = 0.f;
            #pragma unroll
            for (int q = 0; q < 16; ++q) {
                float4 xv = xr[q];
                float4 wa = hw4[j * 16 + q];
                s = fmaf(xv.x, wa.x, s); s = fmaf(xv.y, wa.y, s);
                s = fmaf(xv.z, wa.z, s); s = fmaf(xv.w, wa.w, s);
            }
            if (g == 2) out[OBIN + gpos * 5 + 4] = s + binb[4];
            else        out[ORES + gpos]         = s + resb[0];
        }
    }
}

extern "C" void kernel_launch(void* const* d_in, const int* in_sizes, int n_in,
                              void* d_out, int out_size, void* d_ws, size_t ws_size,
                              hipStream_t stream)
{
    const float* box  = (const float*)d_in[0];
    const float* cls  = (const float*)d_in[1];
    const float* c1w  = (const float*)d_in[2];
    const float* g1   = (const float*)d_in[3];
    const float* b1   = (const float*)d_in[4];
    const float* m1   = (const float*)d_in[5];
    const float* v1   = (const float*)d_in[6];
    const float* c2w  = (const float*)d_in[7];
    const float* g2   = (const float*)d_in[8];
    const float* b2   = (const float*)d_in[9];
    const float* m2   = (const float*)d_in[10];
    const float* v2   = (const float*)d_in[11];
    const float* binw = (const float*)d_in[12];
    const float* binb = (const float*)d_in[13];
    const float* resw = (const float*)d_in[14];
    const float* resb = (const float*)d_in[15];
    float* out = (float*)d_out;
    char* ws = (char*)d_ws;
    if (ws_size < WS_NEEDED) return;

    uint32_t* bits  = (uint32_t*)(ws + OFF_BITS);
    uint32_t* h13   = (uint32_t*)(ws + OFF_H13);
    uint32_t* ctrl  = (uint32_t*)(ws + OFF_CTRL);
    uint32_t* grank = (uint32_t*)(ws + OFF_GRANK);
    uint64_t* cand  = (uint64_t*)(ws + OFF_CAND);

    k_init<<<(NBIN * NB) / 1024, 256, 0, stream>>>((uint4*)h13);
    k_score<<<dim3(HBLK, NB), 256, 0, stream>>>(cls, bits, h13, grank, ctrl);
    k_compact<<<dim3(CBLK, NB), 256, 0, stream>>>(bits, h13, ctrl, cand);
    k_rank1<<<dim3(CAP / 256, 8, NB), 256, 0, stream>>>(cand, ctrl, grank);
    k_rank2<<<dim3(CAP / 256, NB), 256, 0, stream>>>(cand, ctrl, grank, box, cls, out);
    k_conv<<<dim3(64, NB), 256, 0, stream>>>(c1w, g1, b1, m1, v1, c2w, g2, b2, m2, v2,
                                             binw, binb, resw, resb, out);
}